// Round 7
// baseline (152.495 us; speedup 1.0000x reference)
//
#include <hip/hip_runtime.h>
#include <math.h>

#define S_LEN 2048
#define E_DIM 1024
#define NHEAD 16
#define HD 64
#define WIN 128
#define NB 2
#define MTOT (NB * S_LEN)   // 4096
#define NMAT 3072

typedef float f32x4 __attribute__((ext_vector_type(4)));
typedef short bf16x8 __attribute__((ext_vector_type(8)));

#define GLOAD_LDS(g, l) __builtin_amdgcn_global_load_lds( \
    (const __attribute__((address_space(1))) unsigned int*)(g), \
    (__attribute__((address_space(3))) unsigned int*)(l), 16, 0, 0)

__device__ __forceinline__ unsigned short f2bf(float f) {
    unsigned u = __float_as_uint(f);
    u += 0x7fffu + ((u >> 16) & 1u);   // RNE
    return (unsigned short)(u >> 16);
}
__device__ __forceinline__ float bf2f(unsigned short u) {
    return __uint_as_float(((unsigned)u) << 16);
}

// ---------------- fp32 -> bf16 conversion of x and concat(Wq,Wk,Wv) ----------------
__global__ __launch_bounds__(256) void convert_kernel(
    const float* __restrict__ x, const float* __restrict__ wq,
    const float* __restrict__ wk, const float* __restrict__ wv,
    unsigned short* __restrict__ xb, unsigned short* __restrict__ wb)
{
    const int NXQ = MTOT * E_DIM / 4;      // 1048576 quads
    const int NWQ = E_DIM * E_DIM / 4;     // 262144
    const int TOT = NXQ + 3 * NWQ;         // 1835008
    for (int i = blockIdx.x * 256 + threadIdx.x; i < TOT; i += gridDim.x * 256) {
        const float* src; unsigned short* dst; int off;
        if (i < NXQ)               { src = x;  dst = xb;                     off = i; }
        else if (i < NXQ + NWQ)    { src = wq; dst = wb;                     off = i - NXQ; }
        else if (i < NXQ + 2*NWQ)  { src = wk; dst = wb + E_DIM * E_DIM;     off = i - NXQ - NWQ; }
        else                       { src = wv; dst = wb + 2 * E_DIM * E_DIM; off = i - NXQ - 2*NWQ; }
        float4 v = ((const float4*)src)[off];
        ushort4 o;
        o.x = f2bf(v.x); o.y = f2bf(v.y); o.z = f2bf(v.z); o.w = f2bf(v.w);
        ((ushort4*)dst)[off] = o;
    }
}

// ---------------- bf16 MFMA GEMM: Y[m,n] = bias[n] + sum_k A[m,k]*B[n,k] ----------------
// Epilogue stores Q/K/V in the FAITHFUL reshape layout [bh][i][d]:
//   h = (m&2047)>>7, i = ((m&2047)&127)*16 + (n>>6), d = n&63   (reference view() w/o transpose)
__global__ __launch_bounds__(256) void gemm_mfma(
    const unsigned short* __restrict__ Ab, const unsigned short* __restrict__ Bb,
    const float* __restrict__ bq, const float* __restrict__ bk, const float* __restrict__ bv,
    unsigned short* __restrict__ Qb, unsigned short* __restrict__ Kb,
    unsigned short* __restrict__ Vb)
{
    __shared__ __align__(256) unsigned short As[128 * 64];
    __shared__ __align__(256) unsigned short Bs[128 * 64];
    const int tid  = threadIdx.x;
    const int lane = tid & 63;
    const int w    = tid >> 6;
    const int wm   = w & 1, wn = w >> 1;
    const int m0   = blockIdx.y * 128;
    const int n0   = blockIdx.x * 128;
    const int l15  = lane & 15, l4 = lane >> 4;

    f32x4 acc[16] = {};

    for (int k0 = 0; k0 < E_DIM; k0 += 64) {
        #pragma unroll
        for (int is = 0; is < 4; ++is) {
            int gid = is * 256 + tid;
            int r = gid >> 3, sl = gid & 7;
            int gran = sl ^ (r & 7);             // XOR swizzle (granule = 8 bf16 = 16 B)
            int wbs = is * 256 + (tid & 192);    // wave-uniform LDS base (granules)
            GLOAD_LDS(Ab + (size_t)(m0 + r) * E_DIM + k0 + gran * 8, As + wbs * 8);
            GLOAD_LDS(Bb + (size_t)(n0 + r) * E_DIM + k0 + gran * 8, Bs + wbs * 8);
        }
        __syncthreads();
        #pragma unroll
        for (int kk = 0; kk < 2; ++kk) {
            bf16x8 af[4], bfr[4];
            int sa = (kk * 4 + l4) ^ (l15 & 7);
            #pragma unroll
            for (int t = 0; t < 4; ++t) {
                int ra = wm * 64 + t * 16 + l15;
                af[t]  = *(const bf16x8*)&As[ra * 64 + sa * 8];
                int rb = wn * 64 + t * 16 + l15;
                bfr[t] = *(const bf16x8*)&Bs[rb * 64 + sa * 8];
            }
            #pragma unroll
            for (int mt = 0; mt < 4; ++mt)
                #pragma unroll
                for (int nt = 0; nt < 4; ++nt)
                    acc[mt * 4 + nt] = __builtin_amdgcn_mfma_f32_16x16x32_bf16(
                        af[mt], bfr[nt], acc[mt * 4 + nt], 0, 0, 0);
        }
        __syncthreads();
    }

    const int sel = n0 >> 10;
    const float* bias = (sel == 0) ? bq : ((sel == 1) ? bk : bv);
    unsigned short* Yb = (sel == 0) ? Qb : ((sel == 1) ? Kb : Vb);
    const int nbase = (n0 & 1023) + wn * 64;
    #pragma unroll
    for (int mt = 0; mt < 4; ++mt) {
        #pragma unroll
        for (int nt = 0; nt < 4; ++nt) {
            int n = nbase + nt * 16 + l15;      // e index in [0,1024)
            int c = n >> 6, d = n & 63;
            float bb = bias[n];
            #pragma unroll
            for (int r = 0; r < 4; ++r) {
                int m = m0 + wm * 64 + mt * 16 + l4 * 4 + r;
                int b = m >> 11, s = m & 2047;
                int h = s >> 7;
                int i = ((s & 127) << 4) + c;   // faithful reshape
                Yb[(((size_t)(b * 16 + h) * S_LEN + i) << 6) + d] =
                    f2bf(acc[mt * 4 + nt][r] + bb);
            }
        }
    }
}

// ---------------- vtot partials: vtp[seg][bh][d] = sum_{i in seg} V[bh][i][d] ----------------
__global__ __launch_bounds__(256) void vtot_part_kernel(
    const unsigned short* __restrict__ Vb, float* __restrict__ vtp)
{
    const int bh = blockIdx.x, seg = blockIdx.y;   // 32 x 8
    const int d = threadIdx.x & 63, sl = threadIdx.x >> 6;   // 4 i-slices of 64
    const unsigned short* p = Vb + ((size_t)bh * S_LEN + seg * 256 + sl * 64) * HD + d;
    float s = 0.f;
    #pragma unroll 8
    for (int j = 0; j < 64; ++j) s += bf2f(p[(size_t)j * HD]);
    __shared__ float red[4][64];
    red[sl][d] = s;
    __syncthreads();
    if (sl == 0)
        vtp[(seg * NB * NHEAD + bh) * HD + d] = red[0][d] + red[1][d] + red[2][d] + red[3][d];
}

// ---------------- MFMA attention: p'' = win ? e^{s*scale}-1 : 0 ----------------
// out = (sum p'' v + Vtot) / (sum p'' + S).  128-query tile; V transposed in-LDS per chunk.
__global__ __launch_bounds__(256) void attn_mfma(
    const unsigned short* __restrict__ Qb, const unsigned short* __restrict__ Kb,
    const unsigned short* __restrict__ Vb, const float* __restrict__ vtp,
    float* __restrict__ out)
{
    // qps: qs[128*64] (staging, dead after frag extract) UNION ps[4][32*72] (P scratch)
    __shared__ __align__(256) unsigned short qps[9216];
    __shared__ __align__(256) unsigned short ks[2][64 * 64];
    __shared__ __align__(256) unsigned short vts[64 * 64];    // V^T, written by ds_write
    __shared__ __align__(256) unsigned short vscr[64 * 64];   // V rows [j][d], DMA target

    const int qt = blockIdx.x, bh = blockIdx.y;
    const int b = bh >> 4, h = bh & 15;
    const int i0 = qt * 128;
    const int tid = threadIdx.x;
    const int w = tid >> 6, lane = tid & 63;
    const int l15 = lane & 15, quad = lane >> 4;

    const unsigned short* Qp = Qb + (size_t)bh * S_LEN * HD;
    const unsigned short* Kp = Kb + (size_t)bh * S_LEN * HD;
    const unsigned short* Vp = Vb + (size_t)bh * S_LEN * HD;

    // stage Q (128 rows x 64 bf16), granule-XOR swizzled
    #pragma unroll
    for (int it = 0; it < 4; ++it) {
        int gid = it * 256 + tid;
        int r = gid >> 3, sl = gid & 7;
        int gran = sl ^ (r & 7);
        int wbs = it * 256 + (tid & 192);
        GLOAD_LDS(Qp + (size_t)(i0 + r) * HD + gran * 8, qps + wbs * 8);
    }

    const int j_begin = (i0 - WIN > 0) ? i0 - WIN : 0;
    const int j_end   = (i0 + 256 < S_LEN) ? i0 + 256 : S_LEN;
    const int n_ch    = (j_end - j_begin) >> 6;   // 4 (edges) or 6

    // stage chunk 0: K rows -> ks[0], V rows -> vscr (all in-bounds by construction)
    #pragma unroll
    for (int it = 0; it < 2; ++it) {
        int gid = it * 256 + tid;
        int r = gid >> 3, sl = gid & 7;
        int gran = sl ^ (r & 7);
        int wbs = it * 256 + (tid & 192);
        GLOAD_LDS(Kp + (size_t)(j_begin + r) * HD + gran * 8, ks[0] + wbs * 8);
        GLOAD_LDS(Vp + (size_t)(j_begin + r) * HD + gran * 8, vscr + wbs * 8);
    }
    __syncthreads();

    // Q A-fragments: two 16-row subtiles per wave (rows w*32 .. w*32+31)
    bf16x8 aq[2][2];
    #pragma unroll
    for (int q2 = 0; q2 < 2; ++q2) {
        int row = w * 32 + q2 * 16 + l15;
        aq[q2][0] = *(const bf16x8*)&qps[(row * 8 + (quad ^ (row & 7))) * 8];
        aq[q2][1] = *(const bf16x8*)&qps[(row * 8 + ((4 + quad) ^ (row & 7))) * 8];
    }
    bf16x8 bones;
    #pragma unroll
    for (int t = 0; t < 8; ++t) bones[t] = (short)0x3F80;   // bf16 1.0

    f32x4 acc_o[2][4] = {};
    f32x4 acc_sum[2] = {};
    unsigned short* psw = qps + w * 2304;   // per-wave P scratch, 32 rows x stride 72

    const int td = tid & 63;     // d for transpose
    const int toct = tid >> 6;   // j-octet base

    for (int c = 0; c < n_ch; ++c) {
        const int cb = c & 1;
        const int jc0 = j_begin + c * 64;

        // ---- in-LDS transpose: vscr[j][d] -> vts[d][j] (granule-XOR swizzled rows) ----
        #pragma unroll
        for (int pc = 0; pc < 2; ++pc) {
            int oct = toct + pc * 4;
            bf16x8 vv;
            #pragma unroll
            for (int t = 0; t < 8; ++t)
                vv[t] = (short)vscr[(oct * 8 + t) * 64 + (((td >> 3) ^ t) * 8) + (td & 7)];
            *(bf16x8*)&vts[td * 64 + ((oct ^ (td & 7)) * 8)] = vv;
        }
        __syncthreads();   // vts visible; vscr free for next DMA

        if (c + 1 < n_ch) {   // prefetch next chunk, overlapped with QK/exp/PV below
            const int jn0 = jc0 + 64;
            #pragma unroll
            for (int it = 0; it < 2; ++it) {
                int gid = it * 256 + tid;
                int r = gid >> 3, sl = gid & 7;
                int gran = sl ^ (r & 7);
                int wbs = it * 256 + (tid & 192);
                GLOAD_LDS(Kp + (size_t)(jn0 + r) * HD + gran * 8, ks[1 - cb] + wbs * 8);
                GLOAD_LDS(Vp + (size_t)(jn0 + r) * HD + gran * 8, vscr + wbs * 8);
            }
        }

        // ---- QK^T: scores[2 x 16 q][64 j] ----
        f32x4 sacc[2][4] = {};
        const unsigned short* kb = ks[cb];
        #pragma unroll
        for (int kk = 0; kk < 2; ++kk) {
            #pragma unroll
            for (int jt = 0; jt < 4; ++jt) {
                int row = jt * 16 + l15;
                bf16x8 bk = *(const bf16x8*)&kb[(row * 8 + ((kk * 4 + quad) ^ (row & 7))) * 8];
                sacc[0][jt] = __builtin_amdgcn_mfma_f32_16x16x32_bf16(aq[0][kk], bk, sacc[0][jt], 0, 0, 0);
                sacc[1][jt] = __builtin_amdgcn_mfma_f32_16x16x32_bf16(aq[1][kk], bk, sacc[1][jt], 0, 0, 0);
            }
        }

        // ---- p'' = in-window ? e^{s/8}-1 : 0 ; C-layout -> LDS -> A-layout (wave-local) ----
        #pragma unroll
        for (int q2 = 0; q2 < 2; ++q2) {
            #pragma unroll
            for (int jt = 0; jt < 4; ++jt) {
                int jg = jc0 + jt * 16 + l15;
                #pragma unroll
                for (int reg = 0; reg < 4; ++reg) {
                    int i = i0 + w * 32 + q2 * 16 + quad * 4 + reg;
                    bool valid = (jg >= i - WIN) && (jg < i + WIN);   // jg always in [0,S)
                    float p = valid ? __expf(sacc[q2][jt][reg] * 0.125f) - 1.f : 0.f;
                    psw[(q2 * 16 + quad * 4 + reg) * 72 + jt * 16 + l15] = f2bf(p);
                }
            }
        }
        bf16x8 ap[2][2];
        #pragma unroll
        for (int q2 = 0; q2 < 2; ++q2) {
            ap[q2][0] = *(const bf16x8*)&psw[(q2 * 16 + l15) * 72 + quad * 8];
            ap[q2][1] = *(const bf16x8*)&psw[(q2 * 16 + l15) * 72 + 32 + quad * 8];
        }

        // ---- PV + row-sum (ones trick) ----
        #pragma unroll
        for (int kst = 0; kst < 2; ++kst) {
            #pragma unroll
            for (int dt = 0; dt < 4; ++dt) {
                int row = dt * 16 + l15;
                bf16x8 bv_ = *(const bf16x8*)&vts[(row * 8 + ((kst * 4 + quad) ^ (row & 7))) * 8];
                acc_o[0][dt] = __builtin_amdgcn_mfma_f32_16x16x32_bf16(ap[0][kst], bv_, acc_o[0][dt], 0, 0, 0);
                acc_o[1][dt] = __builtin_amdgcn_mfma_f32_16x16x32_bf16(ap[1][kst], bv_, acc_o[1][dt], 0, 0, 0);
            }
            acc_sum[0] = __builtin_amdgcn_mfma_f32_16x16x32_bf16(ap[0][kst], bones, acc_sum[0], 0, 0, 0);
            acc_sum[1] = __builtin_amdgcn_mfma_f32_16x16x32_bf16(ap[1][kst], bones, acc_sum[1], 0, 0, 0);
        }
        __syncthreads();   // drains this chunk's DMA; protects ks/vts reuse
    }

    // ---- epilogue (vtot = sum of 8 partials, L2-hot 64 KB) ----
    float vtv[4];
    #pragma unroll
    for (int dt = 0; dt < 4; ++dt) {
        float s = 0.f;
        #pragma unroll
        for (int sg = 0; sg < 8; ++sg)
            s += vtp[(sg * NB * NHEAD + bh) * HD + dt * 16 + l15];
        vtv[dt] = s;
    }
    #pragma unroll
    for (int q2 = 0; q2 < 2; ++q2) {
        #pragma unroll
        for (int reg = 0; reg < 4; ++reg) {
            int i = i0 + w * 32 + q2 * 16 + quad * 4 + reg;
            float inv = 1.f / (acc_sum[q2][reg] + (float)S_LEN);
            float* op = out + (((size_t)(b * S_LEN + i)) * NHEAD + h) * HD;
            #pragma unroll
            for (int dt = 0; dt < 4; ++dt)
                op[dt * 16 + l15] = (acc_o[q2][dt][reg] + vtv[dt]) * inv;
        }
    }
}

extern "C" void kernel_launch(void* const* d_in, const int* in_sizes, int n_in,
                              void* d_out, int out_size, void* d_ws, size_t ws_size,
                              hipStream_t stream)
{
    const float* x  = (const float*)d_in[0];
    const float* Wq = (const float*)d_in[1];
    const float* bq = (const float*)d_in[2];
    const float* Wk = (const float*)d_in[3];
    const float* bk = (const float*)d_in[4];
    const float* Wv = (const float*)d_in[5];
    const float* bv = (const float*)d_in[6];
    float* out = (float*)d_out;

    const size_t NY = (size_t)MTOT * E_DIM;   // 4194304 elements
    unsigned short* xb  = (unsigned short*)d_ws;
    unsigned short* wb  = xb + NY;                        // 3*E*E = 3145728
    unsigned short* Qb  = wb + (size_t)3 * E_DIM * E_DIM;
    unsigned short* Kb  = Qb + NY;
    unsigned short* Vb  = Kb + NY;
    float* vtp = (float*)(Vb + NY);                       // 8*32*64 fp32 partials

    convert_kernel<<<1792, 256, 0, stream>>>(x, Wq, Wk, Wv, xb, wb);
    gemm_mfma<<<dim3(NMAT / 128, MTOT / 128), 256, 0, stream>>>(xb, wb, bq, bk, bv, Qb, Kb, Vb);
    vtot_part_kernel<<<dim3(NB * NHEAD, 8), 256, 0, stream>>>(Vb, vtp);
    attn_mfma<<<dim3(S_LEN / 128, NB * NHEAD), 256, 0, stream>>>(Qb, Kb, Vb, vtp, out);
}